// Round 3
// baseline (442.033 us; speedup 1.0000x reference)
//
#include <hip/hip_runtime.h>
#include <hip/hip_bf16.h>
#include <math.h>

// Problem constants (fixed by reference)
#define B_TREES 64
#define N_NODES 65536
#define D 1024          // D_MEM == D_HID == 1024
#define D4 (D/4)        // 256 float4 per row
#define PIECE 16        // nodes per wave-piece
#define MAXP (N_NODES/PIECE + B_TREES)   // 4160 max pieces

// ---------------- Kernel 1: serial setup: offsets + piece bases -------------
// lens dtype autodetect: JAX x64-off downcasts int64->int32.
__global__ void setup_kernel(const int* __restrict__ lens32,
                             int* __restrict__ off, int* __restrict__ pbase) {
    if (threadIdx.x == 0 && blockIdx.x == 0) {
        long long s32 = 0;
        for (int b = 0; b < B_TREES; ++b) s32 += lens32[b];
        const bool is32 = (s32 == (long long)N_NODES);
        int acc = 0, pacc = 0;
        off[0] = 0; pbase[0] = 0;
        for (int b = 0; b < B_TREES; ++b) {
            int len = is32 ? lens32[b] : (int)(((const long long*)lens32)[b]);
            acc  += len;
            pacc += (len + PIECE - 1) / PIECE;
            off[b + 1]   = acc;
            pbase[b + 1] = pacc;
        }
    }
}

// ---------------- Kernel 2: emit piece records (parallel over segments) -----
__global__ void pieces_kernel(const int* __restrict__ off, const int* __restrict__ pbase,
                              int* __restrict__ pseg, int* __restrict__ pstart,
                              int* __restrict__ plen) {
    const int b  = blockIdx.x;
    const int s0 = off[b], s1 = off[b + 1];
    const int np = pbase[b + 1] - pbase[b];
    for (int i = threadIdx.x; i < np; i += blockDim.x) {
        int st = s0 + i * PIECE;
        int p  = pbase[b] + i;
        pseg[p]   = b;
        pstart[p] = st;
        plen[p]   = min(PIECE, s1 - st);
    }
}

// ---------------- Kernel 3: v = ds @ W   (v[b][m] = sum_h ds[b][h]*W[h][m]) --
// grid: (4 m-tiles of 256, 16 b-groups of 4, 8 h-chunks of 128); block 256
__global__ void v_kernel(const float* __restrict__ ds, const float* __restrict__ W,
                         float* __restrict__ v) {
    const int m  = blockIdx.x * 256 + threadIdx.x;
    const int b0 = blockIdx.y * 4;
    const int h0 = blockIdx.z * 128;
    float acc[4] = {0.f, 0.f, 0.f, 0.f};
    for (int h = h0; h < h0 + 128; ++h) {
        float wv = W[h * D + m];                 // coalesced
        #pragma unroll
        for (int j = 0; j < 4; ++j)
            acc[j] += ds[(b0 + j) * D + h] * wv; // wave-uniform -> scalar loads
    }
    #pragma unroll
    for (int j = 0; j < 4; ++j)
        atomicAdd(&v[(b0 + j) * D + m], acc[j]);
}

// ---------------- Kernel 4: fused scores + online-softmax context partials ---
// One wave per piece (<=16 nodes, single segment). Lane l covers float4
// indices {l, 64+l, 128+l, 192+l} of the 1024-dim row. Single read of mb:
// the row is dotted with v AND accumulated into the context partial while
// still in registers. No __syncthreads anywhere.
__global__ __launch_bounds__(256) void fused_kernel(
        const float4* __restrict__ mb, const float4* __restrict__ v,
        const int* __restrict__ pseg, const int* __restrict__ pstart,
        const int* __restrict__ plen, const int* __restrict__ pbase,
        float* __restrict__ pm, float* __restrict__ pz, float4* __restrict__ pctx) {
    const int wave = threadIdx.x >> 6;
    const int lane = threadIdx.x & 63;
    const int p    = blockIdx.x * 4 + wave;
    if (p >= pbase[B_TREES]) return;

    const int seg = pseg[p];
    const int s0  = pstart[p];
    const int ln  = plen[p];

    const float4* vrow = v + (size_t)seg * D4;
    const float4 v0 = vrow[lane], v1 = vrow[64 + lane],
                 v2 = vrow[128 + lane], v3 = vrow[192 + lane];

    float4 a0 = make_float4(0.f,0.f,0.f,0.f), a1 = a0, a2 = a0, a3 = a0;
    float rm = -INFINITY, rz = 0.f;

    for (int i = 0; i < ln; ++i) {
        const float4* mrow = mb + (size_t)(s0 + i) * D4;
        const float4 m0 = mrow[lane],       m1 = mrow[64 + lane],
                     m2 = mrow[128 + lane], m3 = mrow[192 + lane];
        float d0 = m0.x*v0.x + m0.y*v0.y + m0.z*v0.z + m0.w*v0.w;
        float d1 = m1.x*v1.x + m1.y*v1.y + m1.z*v1.z + m1.w*v1.w;
        float d2 = m2.x*v2.x + m2.y*v2.y + m2.z*v2.z + m2.w*v2.w;
        float d3 = m3.x*v3.x + m3.y*v3.y + m3.z*v3.z + m3.w*v3.w;
        float d  = (d0 + d1) + (d2 + d3);
        #pragma unroll
        for (int o = 32; o > 0; o >>= 1) d += __shfl_xor(d, o, 64);

        const float nm = fmaxf(rm, d);
        const float sc = __expf(rm - nm);   // first iter: exp(-inf)=0, acc is 0
        const float w  = __expf(d - nm);
        a0.x = a0.x*sc + w*m0.x; a0.y = a0.y*sc + w*m0.y;
        a0.z = a0.z*sc + w*m0.z; a0.w = a0.w*sc + w*m0.w;
        a1.x = a1.x*sc + w*m1.x; a1.y = a1.y*sc + w*m1.y;
        a1.z = a1.z*sc + w*m1.z; a1.w = a1.w*sc + w*m1.w;
        a2.x = a2.x*sc + w*m2.x; a2.y = a2.y*sc + w*m2.y;
        a2.z = a2.z*sc + w*m2.z; a2.w = a2.w*sc + w*m2.w;
        a3.x = a3.x*sc + w*m3.x; a3.y = a3.y*sc + w*m3.y;
        a3.z = a3.z*sc + w*m3.z; a3.w = a3.w*sc + w*m3.w;
        rz = rz*sc + w;
        rm = nm;
    }

    if (lane == 0) { pm[p] = rm; pz[p] = rz; }
    float4* o = pctx + (size_t)p * D4;
    o[lane] = a0; o[64 + lane] = a1; o[128 + lane] = a2; o[192 + lane] = a3;
}

// ---------------- Kernel 5: finalize — merge piece partials per segment ------
// grid = 64 (one per segment), block = 256; thread t owns float4 index t.
__global__ void finalize_kernel(const int* __restrict__ pbase,
                                const float* __restrict__ pm, const float* __restrict__ pz,
                                const float4* __restrict__ pctx, float4* __restrict__ out) {
    const int b  = blockIdx.x;
    const int t  = threadIdx.x;
    const int q0 = pbase[b], q1 = pbase[b + 1];

    float mb_ = -INFINITY;
    for (int q = q0; q < q1; ++q) mb_ = fmaxf(mb_, pm[q]);
    float zb = 0.f;
    for (int q = q0; q < q1; ++q) zb += pz[q] * __expf(pm[q] - mb_);
    const float inv = 1.f / zb;

    float4 acc = make_float4(0.f,0.f,0.f,0.f);
    for (int q = q0; q < q1; ++q) {
        const float s = __expf(pm[q] - mb_);
        const float4 c = pctx[(size_t)q * D4 + t];
        acc.x += s * c.x; acc.y += s * c.y; acc.z += s * c.z; acc.w += s * c.w;
    }
    acc.x *= inv; acc.y *= inv; acc.z *= inv; acc.w *= inv;
    out[(size_t)b * D4 + t] = acc;
}

extern "C" void kernel_launch(void* const* d_in, const int* in_sizes, int n_in,
                              void* d_out, int out_size, void* d_ws, size_t ws_size,
                              hipStream_t stream) {
    const float* mb   = (const float*)d_in[0];       // [N, 1024]
    const float* ds   = (const float*)d_in[1];       // [64, 1024]
    const float* W    = (const float*)d_in[2];       // [1024, 1024]
    const int*   lens = (const int*)d_in[3];         // [64] int32 (autodetect int64)
    float*       out  = (float*)d_out;               // [64, 1024]

    // workspace layout (all offsets in bytes, generously padded/aligned)
    char* ws = (char*)d_ws;
    int*   off    = (int*)(ws + 0);                  // 65 ints
    int*   pbase  = (int*)(ws + 512);                // 65 ints
    float* v      = (float*)(ws + 1024);             // 64*1024 floats = 256 KB
    int*   pseg   = (int*)(ws + 1024 + 262144);              // MAXP ints (pad 32 KB)
    int*   pstart = (int*)(ws + 1024 + 262144 + 32768);      // MAXP ints
    int*   plen   = (int*)(ws + 1024 + 262144 + 65536);      // MAXP ints
    float* pm     = (float*)(ws + 1024 + 262144 + 98304);    // MAXP floats
    float* pz     = (float*)(ws + 1024 + 262144 + 131072);   // MAXP floats
    float4* pctx  = (float4*)(ws + 1024 + 262144 + 163840);  // MAXP*1024 floats ≈ 17 MB

    hipMemsetAsync(v, 0, 64 * D * sizeof(float), stream);  // atomic target

    setup_kernel<<<1, 64, 0, stream>>>(lens, off, pbase);
    pieces_kernel<<<B_TREES, 256, 0, stream>>>(off, pbase, pseg, pstart, plen);

    {
        dim3 grid(4, 16, 8);
        v_kernel<<<grid, 256, 0, stream>>>(ds, W, v);
    }

    fused_kernel<<<(MAXP + 3) / 4, 256, 0, stream>>>(
        (const float4*)mb, (const float4*)v, pseg, pstart, plen, pbase,
        pm, pz, pctx);

    finalize_kernel<<<B_TREES, 256, 0, stream>>>(
        pbase, pm, pz, pctx, (float4*)out);
}

// Round 4
// 437.838 us; speedup vs baseline: 1.0096x; 1.0096x over previous
//
#include <hip/hip_runtime.h>
#include <hip/hip_bf16.h>
#include <math.h>

// Problem constants (fixed by reference)
#define B_TREES 64
#define N_NODES 65536
#define D 1024          // D_MEM == D_HID == 1024
#define D4 (D/4)        // 256 float4 per row
#define PIECE 16        // nodes per wave-piece
#define MAXP (N_NODES/PIECE + B_TREES)   // 4160 max pieces

// ---------------- Kernel 1: parallel setup: scan + piece emission -----------
// One block, 256 threads. Wave 0 (64 lanes) does the prefix scans with
// shuffles (coalesced parallel loads — replaces the 50us serial 1-thread
// version); then all 256 threads emit piece records via LDS binary search.
// lens dtype autodetect: JAX x64-off downcasts int64->int32.
__global__ void setup_kernel(const int* __restrict__ lens32,
                             int* __restrict__ off, int* __restrict__ pbase,
                             int* __restrict__ pseg, int* __restrict__ pstart,
                             int* __restrict__ plen) {
    __shared__ int sh_off[B_TREES + 1];
    __shared__ int sh_pb[B_TREES + 1];

    const int t = threadIdx.x;
    if (t < 64) {
        const int lane = t;
        int l32 = lens32[lane];
        // wave-wide sum to autodetect dtype
        int s = l32;
        #pragma unroll
        for (int o = 32; o > 0; o >>= 1) s += __shfl_xor(s, o, 64);
        const bool is32 = (s == N_NODES);
        int len = is32 ? l32 : (int)(((const long long*)lens32)[lane]);
        // inclusive scan of len
        int scan = len;
        #pragma unroll
        for (int o = 1; o < 64; o <<= 1) {
            int u = __shfl_up(scan, o, 64);
            if (lane >= o) scan += u;
        }
        // inclusive scan of piece counts
        int pc = (len + PIECE - 1) / PIECE;
        int pscan = pc;
        #pragma unroll
        for (int o = 1; o < 64; o <<= 1) {
            int u = __shfl_up(pscan, o, 64);
            if (lane >= o) pscan += u;
        }
        sh_off[lane + 1] = scan;
        sh_pb[lane + 1]  = pscan;
        if (lane == 0) { sh_off[0] = 0; sh_pb[0] = 0; }
        off[lane + 1]   = scan;
        pbase[lane + 1] = pscan;
        if (lane == 0) { off[0] = 0; pbase[0] = 0; }
    }
    __syncthreads();

    const int total = sh_pb[B_TREES];
    for (int p = t; p < total; p += 256) {
        int lo = 0, hi = B_TREES - 1;
        while (lo < hi) {
            int mid = (lo + hi + 1) >> 1;
            if (sh_pb[mid] <= p) lo = mid; else hi = mid - 1;
        }
        const int i  = p - sh_pb[lo];
        const int st = sh_off[lo] + i * PIECE;
        pseg[p]   = lo;
        pstart[p] = st;
        plen[p]   = min(PIECE, sh_off[lo + 1] - st);
    }
}

// ---------------- Kernel 2: v = ds @ W   (v[b][m] = sum_h ds[b][h]*W[h][m]) --
// grid: (4 m-tiles of 256, 16 b-groups of 4, 8 h-chunks of 128); block 256
__global__ void v_kernel(const float* __restrict__ ds, const float* __restrict__ W,
                         float* __restrict__ v) {
    const int m  = blockIdx.x * 256 + threadIdx.x;
    const int b0 = blockIdx.y * 4;
    const int h0 = blockIdx.z * 128;
    float acc[4] = {0.f, 0.f, 0.f, 0.f};
    for (int h = h0; h < h0 + 128; ++h) {
        float wv = W[h * D + m];                 // coalesced
        #pragma unroll
        for (int j = 0; j < 4; ++j)
            acc[j] += ds[(b0 + j) * D + h] * wv; // wave-uniform -> scalar loads
    }
    #pragma unroll
    for (int j = 0; j < 4; ++j)
        atomicAdd(&v[(b0 + j) * D + m], acc[j]);
}

// ---------------- Kernel 3: fused scores + online-softmax context partials ---
// One wave per piece (<=16 nodes, single segment). Lane l covers float4
// indices {l, 64+l, 128+l, 192+l}. Full pieces (ln==16, ~99% of them) take a
// compile-time path processed in PAIRS of rows: 8 loads in flight, two
// independent shuffle-reduce chains, ONE accumulator rescale per 2 rows.
__global__ __launch_bounds__(256) void fused_kernel(
        const float4* __restrict__ mb, const float4* __restrict__ v,
        const int* __restrict__ pseg, const int* __restrict__ pstart,
        const int* __restrict__ plen, const int* __restrict__ pbase,
        float* __restrict__ pm, float* __restrict__ pz, float4* __restrict__ pctx) {
    const int wave = threadIdx.x >> 6;
    const int lane = threadIdx.x & 63;
    const int p    = blockIdx.x * 4 + wave;
    if (p >= pbase[B_TREES]) return;

    const int seg = pseg[p];
    const int s0  = pstart[p];
    const int ln  = plen[p];

    const float4* vrow = v + (size_t)seg * D4;
    const float4 v0 = vrow[lane], v1 = vrow[64 + lane],
                 v2 = vrow[128 + lane], v3 = vrow[192 + lane];

    float4 a0 = make_float4(0.f,0.f,0.f,0.f), a1 = a0, a2 = a0, a3 = a0;
    float rm = -INFINITY, rz = 0.f;

    const float4* base = mb + (size_t)s0 * D4;

    if (ln == PIECE) {
        #pragma unroll 2
        for (int i = 0; i < PIECE; i += 2) {
            const float4* rA = base + (size_t)i * D4;
            const float4* rB = rA + D4;
            const float4 A0 = rA[lane],       A1 = rA[64 + lane],
                         A2 = rA[128 + lane], A3 = rA[192 + lane];
            const float4 B0 = rB[lane],       B1 = rB[64 + lane],
                         B2 = rB[128 + lane], B3 = rB[192 + lane];
            float dA = (A0.x*v0.x + A0.y*v0.y + A0.z*v0.z + A0.w*v0.w)
                     + (A1.x*v1.x + A1.y*v1.y + A1.z*v1.z + A1.w*v1.w)
                     + (A2.x*v2.x + A2.y*v2.y + A2.z*v2.z + A2.w*v2.w)
                     + (A3.x*v3.x + A3.y*v3.y + A3.z*v3.z + A3.w*v3.w);
            float dB = (B0.x*v0.x + B0.y*v0.y + B0.z*v0.z + B0.w*v0.w)
                     + (B1.x*v1.x + B1.y*v1.y + B1.z*v1.z + B1.w*v1.w)
                     + (B2.x*v2.x + B2.y*v2.y + B2.z*v2.z + B2.w*v2.w)
                     + (B3.x*v3.x + B3.y*v3.y + B3.z*v3.z + B3.w*v3.w);
            #pragma unroll
            for (int o = 32; o > 0; o >>= 1) {   // two independent chains interleave
                dA += __shfl_xor(dA, o, 64);
                dB += __shfl_xor(dB, o, 64);
            }
            const float nm = fmaxf(rm, fmaxf(dA, dB));
            const float sc = __expf(rm - nm);    // first iter: exp(-inf)=0
            const float wA = __expf(dA - nm);
            const float wB = __expf(dB - nm);
            a0.x = a0.x*sc + wA*A0.x + wB*B0.x; a0.y = a0.y*sc + wA*A0.y + wB*B0.y;
            a0.z = a0.z*sc + wA*A0.z + wB*B0.z; a0.w = a0.w*sc + wA*A0.w + wB*B0.w;
            a1.x = a1.x*sc + wA*A1.x + wB*B1.x; a1.y = a1.y*sc + wA*A1.y + wB*B1.y;
            a1.z = a1.z*sc + wA*A1.z + wB*B1.z; a1.w = a1.w*sc + wA*A1.w + wB*B1.w;
            a2.x = a2.x*sc + wA*A2.x + wB*B2.x; a2.y = a2.y*sc + wA*A2.y + wB*B2.y;
            a2.z = a2.z*sc + wA*A2.z + wB*B2.z; a2.w = a2.w*sc + wA*A2.w + wB*B2.w;
            a3.x = a3.x*sc + wA*A3.x + wB*B3.x; a3.y = a3.y*sc + wA*A3.y + wB*B3.y;
            a3.z = a3.z*sc + wA*A3.z + wB*B3.z; a3.w = a3.w*sc + wA*A3.w + wB*B3.w;
            rz = rz*sc + wA + wB;
            rm = nm;
        }
    } else {
        for (int i = 0; i < ln; ++i) {
            const float4* mrow = base + (size_t)i * D4;
            const float4 m0 = mrow[lane],       m1 = mrow[64 + lane],
                         m2 = mrow[128 + lane], m3 = mrow[192 + lane];
            float d = (m0.x*v0.x + m0.y*v0.y + m0.z*v0.z + m0.w*v0.w)
                    + (m1.x*v1.x + m1.y*v1.y + m1.z*v1.z + m1.w*v1.w)
                    + (m2.x*v2.x + m2.y*v2.y + m2.z*v2.z + m2.w*v2.w)
                    + (m3.x*v3.x + m3.y*v3.y + m3.z*v3.z + m3.w*v3.w);
            #pragma unroll
            for (int o = 32; o > 0; o >>= 1) d += __shfl_xor(d, o, 64);
            const float nm = fmaxf(rm, d);
            const float sc = __expf(rm - nm);
            const float w  = __expf(d - nm);
            a0.x = a0.x*sc + w*m0.x; a0.y = a0.y*sc + w*m0.y;
            a0.z = a0.z*sc + w*m0.z; a0.w = a0.w*sc + w*m0.w;
            a1.x = a1.x*sc + w*m1.x; a1.y = a1.y*sc + w*m1.y;
            a1.z = a1.z*sc + w*m1.z; a1.w = a1.w*sc + w*m1.w;
            a2.x = a2.x*sc + w*m2.x; a2.y = a2.y*sc + w*m2.y;
            a2.z = a2.z*sc + w*m2.z; a2.w = a2.w*sc + w*m2.w;
            a3.x = a3.x*sc + w*m3.x; a3.y = a3.y*sc + w*m3.y;
            a3.z = a3.z*sc + w*m3.z; a3.w = a3.w*sc + w*m3.w;
            rz = rz*sc + w;
            rm = nm;
        }
    }

    if (lane == 0) { pm[p] = rm; pz[p] = rz; }
    float4* o = pctx + (size_t)p * D4;
    o[lane] = a0; o[64 + lane] = a1; o[128 + lane] = a2; o[192 + lane] = a3;
}

// ---------------- Kernel 4: finalize — merge piece partials per segment ------
// grid = 64 (one per segment), block = 256; thread t owns float4 index t.
__global__ void finalize_kernel(const int* __restrict__ pbase,
                                const float* __restrict__ pm, const float* __restrict__ pz,
                                const float4* __restrict__ pctx, float4* __restrict__ out) {
    const int b  = blockIdx.x;
    const int t  = threadIdx.x;
    const int q0 = pbase[b], q1 = pbase[b + 1];

    float mb_ = -INFINITY;
    for (int q = q0; q < q1; ++q) mb_ = fmaxf(mb_, pm[q]);
    float zb = 0.f;
    for (int q = q0; q < q1; ++q) zb += pz[q] * __expf(pm[q] - mb_);
    const float inv = 1.f / zb;

    float4 acc = make_float4(0.f,0.f,0.f,0.f);
    for (int q = q0; q < q1; ++q) {
        const float s = __expf(pm[q] - mb_);
        const float4 c = pctx[(size_t)q * D4 + t];
        acc.x += s * c.x; acc.y += s * c.y; acc.z += s * c.z; acc.w += s * c.w;
    }
    acc.x *= inv; acc.y *= inv; acc.z *= inv; acc.w *= inv;
    out[(size_t)b * D4 + t] = acc;
}

extern "C" void kernel_launch(void* const* d_in, const int* in_sizes, int n_in,
                              void* d_out, int out_size, void* d_ws, size_t ws_size,
                              hipStream_t stream) {
    const float* mb   = (const float*)d_in[0];       // [N, 1024]
    const float* ds   = (const float*)d_in[1];       // [64, 1024]
    const float* W    = (const float*)d_in[2];       // [1024, 1024]
    const int*   lens = (const int*)d_in[3];         // [64] int32 (autodetect int64)
    float*       out  = (float*)d_out;               // [64, 1024]

    // workspace layout (bytes, padded/aligned)
    char* ws = (char*)d_ws;
    int*   off    = (int*)(ws + 0);                  // 65 ints
    int*   pbase  = (int*)(ws + 512);                // 65 ints
    float* v      = (float*)(ws + 1024);             // 64*1024 floats = 256 KB
    int*   pseg   = (int*)(ws + 1024 + 262144);              // MAXP ints
    int*   pstart = (int*)(ws + 1024 + 262144 + 32768);      // MAXP ints
    int*   plen   = (int*)(ws + 1024 + 262144 + 65536);      // MAXP ints
    float* pm     = (float*)(ws + 1024 + 262144 + 98304);    // MAXP floats
    float* pz     = (float*)(ws + 1024 + 262144 + 131072);   // MAXP floats
    float4* pctx  = (float4*)(ws + 1024 + 262144 + 163840);  // MAXP*1024 floats ~= 17 MB

    hipMemsetAsync(v, 0, 64 * D * sizeof(float), stream);  // atomic target

    setup_kernel<<<1, 256, 0, stream>>>(lens, off, pbase, pseg, pstart, plen);

    {
        dim3 grid(4, 16, 8);
        v_kernel<<<grid, 256, 0, stream>>>(ds, W, v);
    }

    fused_kernel<<<(MAXP + 3) / 4, 256, 0, stream>>>(
        (const float4*)mb, (const float4*)v, pseg, pstart, plen, pbase,
        pm, pz, pctx);

    finalize_kernel<<<B_TREES, 256, 0, stream>>>(
        pbase, pm, pz, pctx, (float4*)out);
}